// Round 1
// baseline (784.740 us; speedup 1.0000x reference)
//
#include <hip/hip_runtime.h>
#include <math.h>

#define S 1024
#define E 1024
#define H 32
#define KSEL 8
#define D 128
#define HD 4096      // H*D
#define SK 8192      // S*KSEL
#define MAXL 1024    // max entries per head (each token picks a head at most once)
#define ATTN_SCALE 0.08838834764831845f  // 1/sqrt(128)

// ---------------- router: logits, softmax stats, top-k, head weights, aux partials ----------------
__global__ __launch_bounds__(256) void router_kernel(
    const float* __restrict__ x, const float* __restrict__ Wr,
    int* __restrict__ head_idx, float* __restrict__ head_w,
    float* __restrict__ accum)   // [0..31] p_sum, [32..63] f_cnt, [64] ent, [65] z
{
    int s = blockIdx.x;
    int tid = threadIdx.x;
    int h = tid & 31, i = tid >> 5;
    const float* xr = x + s * E;
    float partial = 0.f;
    for (int e = i; e < E; e += 8)
        partial += xr[e] * Wr[e * H + h];
    __shared__ float red[256];
    red[tid] = partial;
    __syncthreads();
    __shared__ float slog[H], sexp[H], scopy[H], entt[H];
    __shared__ float sm, sZ;
    if (tid < H) {
        float l = 0.f;
        #pragma unroll
        for (int j = 0; j < 8; ++j) l += red[j * 32 + tid];
        slog[tid] = l; scopy[tid] = l;
    }
    __syncthreads();
    if (tid == 0) {
        float m = slog[0];
        for (int j = 1; j < H; ++j) m = fmaxf(m, slog[j]);
        sm = m;
    }
    __syncthreads();
    if (tid < H) sexp[tid] = expf(slog[tid] - sm);
    __syncthreads();
    if (tid == 0) {
        float Z = 0.f;
        for (int j = 0; j < H; ++j) Z += sexp[j];
        sZ = Z;
        float lse = sm + logf(Z);
        atomicAdd(&accum[65], lse * lse);
    }
    __syncthreads();
    if (tid < H) {
        float p = sexp[tid] / sZ;
        atomicAdd(&accum[tid], p);
        entt[tid] = p * logf(p + 1e-8f);
    }
    __syncthreads();
    if (tid == 0) {
        float es = 0.f;
        for (int j = 0; j < H; ++j) es += entt[j];
        atomicAdd(&accum[64], es);
        // top-k (descending, ties -> lowest index, matching jax.lax.top_k)
        float tv[KSEL]; int ti[KSEL];
        for (int j = 0; j < KSEL; ++j) {
            float bv = -INFINITY; int bi = 0;
            for (int hh = 0; hh < H; ++hh)
                if (scopy[hh] > bv) { bv = scopy[hh]; bi = hh; }
            tv[j] = bv; ti[j] = bi; scopy[bi] = -INFINITY;
        }
        float m2 = tv[0], Z2 = 0.f, w[KSEL];
        #pragma unroll
        for (int j = 0; j < KSEL; ++j) { w[j] = expf(tv[j] - m2); Z2 += w[j]; }
        #pragma unroll
        for (int j = 0; j < KSEL; ++j) {
            head_idx[s * KSEL + j] = ti[j];
            head_w[s * KSEL + j] = w[j] / Z2;
        }
        atomicAdd(&accum[32 + ti[0]], 1.0f);
    }
}

// ---------------- per-head ordered lists, ranks, RoPE positions, updated counts ----------------
__global__ __launch_bounds__(256) void order_kernel(
    const int* __restrict__ head_idx, const int* __restrict__ head_counts,
    int* __restrict__ order, int* __restrict__ rank, int* __restrict__ pos,
    int* __restrict__ hlen, float* __restrict__ out_counts)
{
    int h = blockIdx.x, tid = threadIdx.x;
    __shared__ int sc[256];
    __shared__ int base;
    if (tid == 0) base = 0;
    __syncthreads();
    int hc = head_counts[h];
    for (int c0 = 0; c0 < SK; c0 += 256) {
        int i = c0 + tid;
        int pred = (head_idx[i] == h) ? 1 : 0;
        sc[tid] = pred;
        __syncthreads();
        // Hillis-Steele inclusive scan
        for (int off = 1; off < 256; off <<= 1) {
            int v = 0;
            if (tid >= off) v = sc[tid - off];
            __syncthreads();
            sc[tid] += v;
            __syncthreads();
        }
        int myr = base + sc[tid] - pred;
        if (pred) {
            order[h * MAXL + myr] = i;
            rank[i] = myr;
            int p = myr + hc;
            pos[i] = p < 0 ? 0 : (p > 8191 ? 8191 : p);
        }
        __syncthreads();
        if (tid == 0) base += sc[255];
        __syncthreads();
    }
    if (tid == 0) {
        hlen[h] = base;
        out_counts[h] = (float)(hc + base);  // updated_counts as float in d_out
    }
}

// ---------------- gathered QKV projection: per-head grouped GEMM (64x64 tile, BK=16) ----------------
__global__ __launch_bounds__(256) void qkv_gemm(
    const float* __restrict__ x, const float* __restrict__ Wq,
    const float* __restrict__ Wk, const float* __restrict__ Wv,
    const int* __restrict__ order, const int* __restrict__ hlen,
    float* __restrict__ qg, float* __restrict__ kg, float* __restrict__ vg)
{
    int rt = blockIdx.x, ct = blockIdx.y, h = blockIdx.z;
    int len = hlen[h];
    int row0 = rt * 64;
    if (row0 >= len) return;
    int col0 = ct * 64;                 // 0..383 across q|k|v
    const float* W; float* dst;
    if (col0 < 128)      { W = Wq; dst = qg; }
    else if (col0 < 256) { W = Wk; dst = kg; }
    else                 { W = Wv; dst = vg; }
    int d0 = col0 & 127;
    int tid = threadIdx.x;
    __shared__ int stok[64], sflat[64];
    if (tid < 64) {
        int r = row0 + tid;
        if (r < len) { int f = order[h * MAXL + r]; sflat[tid] = f; stok[tid] = f >> 3; }
        else         { sflat[tid] = -1; stok[tid] = 0; }
    }
    __shared__ float As[16][65];
    __shared__ float Bs[16][64];
    float acc[4][4] = {{0.f}};
    int tx = tid & 15, ty = tid >> 4;
    __syncthreads();
    const float* Wb = W + h * D + d0;
    for (int kk = 0; kk < E; kk += 16) {
        #pragma unroll
        for (int it = 0; it < 4; ++it) {
            int id = it * 256 + tid;
            int r = id >> 4, k = id & 15;
            As[k][r] = x[stok[r] * E + kk + k];
        }
        #pragma unroll
        for (int it = 0; it < 4; ++it) {
            int id = it * 256 + tid;
            int k = id >> 6, c = id & 63;
            Bs[k][c] = Wb[(size_t)(kk + k) * HD + c];
        }
        __syncthreads();
        #pragma unroll
        for (int k = 0; k < 16; ++k) {
            float a[4], b[4];
            #pragma unroll
            for (int ii = 0; ii < 4; ++ii) a[ii] = As[k][ty * 4 + ii];
            #pragma unroll
            for (int jj = 0; jj < 4; ++jj) b[jj] = Bs[k][tx * 4 + jj];
            #pragma unroll
            for (int ii = 0; ii < 4; ++ii)
                #pragma unroll
                for (int jj = 0; jj < 4; ++jj)
                    acc[ii][jj] += a[ii] * b[jj];
        }
        __syncthreads();
    }
    #pragma unroll
    for (int ii = 0; ii < 4; ++ii) {
        int r = ty * 4 + ii;
        int f = sflat[r];
        if (f >= 0) {
            #pragma unroll
            for (int jj = 0; jj < 4; ++jj)
                dst[f * D + d0 + tx * 4 + jj] = acc[ii][jj];
        }
    }
}

// ---------------- RoPE on gathered q,k ----------------
__global__ __launch_bounds__(256) void rope_kernel(
    const int* __restrict__ pos, float* __restrict__ qg, float* __restrict__ kg)
{
    int gid = blockIdx.x * 256 + threadIdx.x;  // SK*64 threads: (entry, dim-pair)
    int i = gid >> 6, d2 = gid & 63;
    float p = (float)pos[i];
    float inv = powf(10000.0f, -(float)(2 * d2) / 128.0f);
    float ang = p * inv;
    float c = cosf(ang), sn = sinf(ang);
    float* q = qg + i * D;
    float q1 = q[d2], q2 = q[d2 + 64];
    q[d2]      = q1 * c - q2 * sn;
    q[d2 + 64] = q2 * c + q1 * sn;
    float* kp = kg + i * D;
    float k1 = kp[d2], k2 = kp[d2 + 64];
    kp[d2]      = k1 * c - k2 * sn;
    kp[d2 + 64] = k2 * c + k1 * sn;
}

// ---------------- streaming per-row attention (one wave per query row, online softmax) ----------------
__global__ __launch_bounds__(64) void attn_kernel(
    const float* __restrict__ qg, const float* __restrict__ kg, const float* __restrict__ vg,
    const int* __restrict__ head_idx, const int* __restrict__ rank,
    const int* __restrict__ order, const float* __restrict__ head_w,
    float* __restrict__ ao)
{
    int i = blockIdx.x;
    int lane = threadIdx.x;
    int h = head_idx[i];
    int r = rank[i];
    const int* ord = order + h * MAXL;
    float q0 = qg[i * D + lane], q1 = qg[i * D + 64 + lane];
    float m = -INFINITY, l = 0.f, o0 = 0.f, o1 = 0.f;
    for (int j = 0; j <= r; ++j) {
        int kidx = ord[j];
        float k0 = kg[kidx * D + lane], k1 = kg[kidx * D + 64 + lane];
        float part = q0 * k0 + q1 * k1;
        #pragma unroll
        for (int off = 32; off > 0; off >>= 1)
            part += __shfl_xor(part, off, 64);
        float sc = part * ATTN_SCALE;
        float mn = fmaxf(m, sc);
        float alpha = expf(m - mn);
        float w = expf(sc - mn);
        float v0 = vg[kidx * D + lane], v1 = vg[kidx * D + 64 + lane];
        l = l * alpha + w;
        o0 = o0 * alpha + w * v0;
        o1 = o1 * alpha + w * v1;
        m = mn;
    }
    float scale = head_w[i] / l;
    ao[i * D + lane]      = o0 * scale;
    ao[i * D + 64 + lane] = o1 * scale;
}

// ---------------- output projection: (S x 1024) @ Wo (1024 x 1024) ----------------
__global__ __launch_bounds__(256) void out_gemm(
    const float* __restrict__ A, const float* __restrict__ B, float* __restrict__ C)
{
    int rt = blockIdx.x, ct = blockIdx.y;
    int tid = threadIdx.x;
    __shared__ float As[16][65];
    __shared__ float Bs[16][64];
    float acc[4][4] = {{0.f}};
    int tx = tid & 15, ty = tid >> 4;
    for (int kk = 0; kk < 1024; kk += 16) {
        #pragma unroll
        for (int it = 0; it < 4; ++it) {
            int id = it * 256 + tid;
            int r = id >> 4, k = id & 15;
            As[k][r] = A[(rt * 64 + r) * 1024 + kk + k];
        }
        #pragma unroll
        for (int it = 0; it < 4; ++it) {
            int id = it * 256 + tid;
            int k = id >> 6, c = id & 63;
            Bs[k][c] = B[(kk + k) * 1024 + ct * 64 + c];
        }
        __syncthreads();
        #pragma unroll
        for (int k = 0; k < 16; ++k) {
            float a[4], b[4];
            #pragma unroll
            for (int ii = 0; ii < 4; ++ii) a[ii] = As[k][ty * 4 + ii];
            #pragma unroll
            for (int jj = 0; jj < 4; ++jj) b[jj] = Bs[k][tx * 4 + jj];
            #pragma unroll
            for (int ii = 0; ii < 4; ++ii)
                #pragma unroll
                for (int jj = 0; jj < 4; ++jj)
                    acc[ii][jj] += a[ii] * b[jj];
        }
        __syncthreads();
    }
    #pragma unroll
    for (int ii = 0; ii < 4; ++ii)
        #pragma unroll
        for (int jj = 0; jj < 4; ++jj)
            C[(rt * 64 + ty * 4 + ii) * 1024 + ct * 64 + tx * 4 + jj] = acc[ii][jj];
}

// ---------------- aux loss finalize ----------------
__global__ void aux_kernel(const float* __restrict__ accum, float* __restrict__ out_aux)
{
    if (threadIdx.x == 0 && blockIdx.x == 0) {
        float bal = 0.f;
        for (int h = 0; h < H; ++h)
            bal += (accum[32 + h] / (float)S) * (accum[h] / (float)S);
        bal *= (float)H;
        float ent_loss = accum[64] / (float)S;   // = -mean(entropy)
        float z = accum[65] / (float)S * 0.01f;
        out_aux[0] = 0.01f * bal + 0.01f * ent_loss + z;
    }
}

extern "C" void kernel_launch(void* const* d_in, const int* in_sizes, int n_in,
                              void* d_out, int out_size, void* d_ws, size_t ws_size,
                              hipStream_t stream)
{
    const float* x  = (const float*)d_in[0];
    const float* Wq = (const float*)d_in[1];
    const float* Wk = (const float*)d_in[2];
    const float* Wv = (const float*)d_in[3];
    const float* Wr = (const float*)d_in[4];
    const float* Wo = (const float*)d_in[5];
    const int* head_counts = (const int*)d_in[6];
    float* out = (float*)d_out;

    // workspace layout
    float* qg     = (float*)d_ws;        // SK*D
    float* kg     = qg + SK * D;
    float* vg     = kg + SK * D;
    float* ao     = vg + SK * D;         // attention output * head_w, laid out as (S, K*D)
    float* head_w = ao + SK * D;         // SK
    float* accum  = head_w + SK;         // 128
    int* head_idx = (int*)(accum + 128); // SK
    int* rank     = head_idx + SK;       // SK
    int* pos      = rank + SK;           // SK
    int* order    = pos + SK;            // H*MAXL
    int* hlen     = order + H * MAXL;    // H

    hipMemsetAsync(accum, 0, 128 * sizeof(float), stream);

    router_kernel<<<S, 256, 0, stream>>>(x, Wr, head_idx, head_w, accum);
    order_kernel<<<H, 256, 0, stream>>>(head_idx, head_counts, order, rank, pos, hlen,
                                        out + (size_t)S * E);
    qkv_gemm<<<dim3(16, 6, H), 256, 0, stream>>>(x, Wq, Wk, Wv, order, hlen, qg, kg, vg);
    rope_kernel<<<SK * 64 / 256, 256, 0, stream>>>(pos, qg, kg);
    attn_kernel<<<SK, 64, 0, stream>>>(qg, kg, vg, head_idx, rank, order, head_w, ao);
    out_gemm<<<dim3(16, 16), 256, 0, stream>>>(ao, Wo, out);
    aux_kernel<<<1, 64, 0, stream>>>(accum, out + (size_t)S * E + H);
}

// Round 2
// 581.567 us; speedup vs baseline: 1.3494x; 1.3494x over previous
//
#include <hip/hip_runtime.h>
#include <math.h>

#define S 1024
#define E 1024
#define H 32
#define KSEL 8
#define D 128
#define HD 4096      // H*D
#define SK 8192      // S*KSEL
#define MAXL 1024
#define ATTN_SCALE 0.08838834764831845f  // 1/sqrt(128)

typedef _Float16 half8 __attribute__((ext_vector_type(8)));
typedef _Float16 half4 __attribute__((ext_vector_type(4)));
typedef float floatx4 __attribute__((ext_vector_type(4)));
typedef float f4 __attribute__((ext_vector_type(4)));

// ---------------- router ----------------
__global__ __launch_bounds__(256) void router_kernel(
    const float* __restrict__ x, const float* __restrict__ Wr,
    int* __restrict__ head_idx, float* __restrict__ head_w,
    float* __restrict__ accum)   // [0..31] p_sum, [32..63] f_cnt, [64] ent, [65] z
{
    int s = blockIdx.x;
    int tid = threadIdx.x;
    int h = tid & 31, i = tid >> 5;
    const float* xr = x + s * E;
    float partial = 0.f;
    for (int e = i; e < E; e += 8)
        partial += xr[e] * Wr[e * H + h];
    __shared__ float red[256];
    red[tid] = partial;
    __syncthreads();
    __shared__ float slog[H], sexp[H], scopy[H], entt[H];
    __shared__ float sm, sZ;
    if (tid < H) {
        float l = 0.f;
        #pragma unroll
        for (int j = 0; j < 8; ++j) l += red[j * 32 + tid];
        slog[tid] = l; scopy[tid] = l;
    }
    __syncthreads();
    if (tid == 0) {
        float m = slog[0];
        for (int j = 1; j < H; ++j) m = fmaxf(m, slog[j]);
        sm = m;
    }
    __syncthreads();
    if (tid < H) sexp[tid] = expf(slog[tid] - sm);
    __syncthreads();
    if (tid == 0) {
        float Z = 0.f;
        for (int j = 0; j < H; ++j) Z += sexp[j];
        sZ = Z;
        float lse = sm + logf(Z);
        atomicAdd(&accum[65], lse * lse);
    }
    __syncthreads();
    if (tid < H) {
        float p = sexp[tid] / sZ;
        atomicAdd(&accum[tid], p);
        entt[tid] = p * logf(p + 1e-8f);
    }
    __syncthreads();
    if (tid == 0) {
        float es = 0.f;
        for (int j = 0; j < H; ++j) es += entt[j];
        atomicAdd(&accum[64], es);
        float tv[KSEL]; int ti[KSEL];
        for (int j = 0; j < KSEL; ++j) {
            float bv = -INFINITY; int bi = 0;
            for (int hh = 0; hh < H; ++hh)
                if (scopy[hh] > bv) { bv = scopy[hh]; bi = hh; }
            tv[j] = bv; ti[j] = bi; scopy[bi] = -INFINITY;
        }
        float m2 = tv[0], Z2 = 0.f, w[KSEL];
        #pragma unroll
        for (int j = 0; j < KSEL; ++j) { w[j] = expf(tv[j] - m2); Z2 += w[j]; }
        #pragma unroll
        for (int j = 0; j < KSEL; ++j) {
            head_idx[s * KSEL + j] = ti[j];
            head_w[s * KSEL + j] = w[j] / Z2;
        }
        atomicAdd(&accum[32 + ti[0]], 1.0f);
    }
}

// ---------------- per-head ordered lists ----------------
__global__ __launch_bounds__(256) void order_kernel(
    const int* __restrict__ head_idx, const int* __restrict__ head_counts,
    int* __restrict__ order, int* __restrict__ rank, int* __restrict__ pos,
    int* __restrict__ hlen, float* __restrict__ out_counts)
{
    int h = blockIdx.x, tid = threadIdx.x;
    __shared__ int sc[256];
    __shared__ int base;
    if (tid == 0) base = 0;
    __syncthreads();
    int hc = head_counts[h];
    for (int c0 = 0; c0 < SK; c0 += 256) {
        int i = c0 + tid;
        int pred = (head_idx[i] == h) ? 1 : 0;
        sc[tid] = pred;
        __syncthreads();
        for (int off = 1; off < 256; off <<= 1) {
            int v = 0;
            if (tid >= off) v = sc[tid - off];
            __syncthreads();
            sc[tid] += v;
            __syncthreads();
        }
        int myr = base + sc[tid] - pred;
        if (pred) {
            order[h * MAXL + myr] = i;
            rank[i] = myr;
            int p = myr + hc;
            pos[i] = p < 0 ? 0 : (p > 8191 ? 8191 : p);
        }
        __syncthreads();
        if (tid == 0) base += sc[255];
        __syncthreads();
    }
    if (tid == 0) {
        hlen[h] = base;
        out_counts[h] = (float)(hc + base);
    }
}

// ---------------- fp32 -> fp16 elementwise (x) ----------------
__global__ __launch_bounds__(256) void conv_x_kernel(const float* __restrict__ x,
                                                     _Float16* __restrict__ xh)
{
    int i = (blockIdx.x * 256 + threadIdx.x) * 4;
    f4 v = *(const f4*)&x[i];
    half4 o;
    o.x = (_Float16)v.x; o.y = (_Float16)v.y; o.z = (_Float16)v.z; o.w = (_Float16)v.w;
    *(half4*)&xh[i] = o;
}

// ---------------- transpose + convert: W (1024 x C fp32) -> T (C x 1024 fp16) ----------------
__global__ __launch_bounds__(256) void convT_kernel(const float* __restrict__ W,
                                                    _Float16* __restrict__ T, int C)
{
    int r0 = blockIdx.x * 64, c0 = blockIdx.y * 64;
    int t = threadIdx.x;
    __shared__ float tile[64][65];
    #pragma unroll
    for (int p = 0; p < 4; ++p) {
        int idx = p * 256 + t;
        int r = idx >> 4, cq = (idx & 15) * 4;
        f4 v = *(const f4*)&W[(size_t)(r0 + r) * C + c0 + cq];
        tile[r][cq] = v.x; tile[r][cq + 1] = v.y; tile[r][cq + 2] = v.z; tile[r][cq + 3] = v.w;
    }
    __syncthreads();
    #pragma unroll
    for (int p = 0; p < 4; ++p) {
        int idx = p * 256 + t;
        int c = idx >> 4, rq = (idx & 15) * 4;
        half4 o;
        o.x = (_Float16)tile[rq][c];
        o.y = (_Float16)tile[rq + 1][c];
        o.z = (_Float16)tile[rq + 2][c];
        o.w = (_Float16)tile[rq + 3][c];
        *(half4*)&T[(size_t)(c0 + c) * 1024 + r0 + rq] = o;
    }
}

// ---------------- gathered QKV projection via MFMA fp16 ----------------
// Wt layout: [qkv][h][d][e] fp16 (k-contiguous).  Block: 32 rows x 128 cols, 4 waves.
__global__ __launch_bounds__(256) void qkv_mfma(
    const _Float16* __restrict__ xh, const _Float16* __restrict__ Wt,
    const int* __restrict__ order, const int* __restrict__ hlen,
    float* __restrict__ qg, float* __restrict__ kg, float* __restrict__ vg)
{
    int rt = blockIdx.x, qkv = blockIdx.y, h = blockIdx.z;
    int len = hlen[h], row0 = rt * 32;
    if (row0 >= len) return;
    float* dst = (qkv == 0) ? qg : (qkv == 1) ? kg : vg;
    int tid = threadIdx.x, wave = tid >> 6, lane = tid & 63;
    int quad = lane >> 4, l16 = lane & 15;
    __shared__ int sflat[32];
    if (tid < 32) { int r = row0 + tid; sflat[tid] = (r < len) ? order[h * MAXL + r] : -1; }
    __syncthreads();
    const _Float16* Arow[2];
    #pragma unroll
    for (int mt = 0; mt < 2; ++mt) {
        int f = sflat[mt * 16 + l16];
        int tok = (f < 0) ? 0 : (f >> 3);
        Arow[mt] = xh + (size_t)tok * E;
    }
    const _Float16* Brow[2];
    #pragma unroll
    for (int nt = 0; nt < 2; ++nt) {
        int cb = wave * 32 + nt * 16 + l16;
        Brow[nt] = Wt + (size_t)((qkv * H + h) * D + cb) * E;
    }
    floatx4 acc[2][2] = {};
    int q8 = quad * 8;
    half8 a[2], b[2], a2[2], b2[2];
    a[0] = *(const half8*)(Arow[0] + q8);
    a[1] = *(const half8*)(Arow[1] + q8);
    b[0] = *(const half8*)(Brow[0] + q8);
    b[1] = *(const half8*)(Brow[1] + q8);
    for (int k0 = 0; k0 < E - 32; k0 += 32) {
        int kn = k0 + 32 + q8;
        a2[0] = *(const half8*)(Arow[0] + kn);
        a2[1] = *(const half8*)(Arow[1] + kn);
        b2[0] = *(const half8*)(Brow[0] + kn);
        b2[1] = *(const half8*)(Brow[1] + kn);
        #pragma unroll
        for (int mt = 0; mt < 2; ++mt)
            #pragma unroll
            for (int nt = 0; nt < 2; ++nt)
                acc[mt][nt] = __builtin_amdgcn_mfma_f32_16x16x32_f16(a[mt], b[nt], acc[mt][nt], 0, 0, 0);
        a[0] = a2[0]; a[1] = a2[1]; b[0] = b2[0]; b[1] = b2[1];
    }
    #pragma unroll
    for (int mt = 0; mt < 2; ++mt)
        #pragma unroll
        for (int nt = 0; nt < 2; ++nt)
            acc[mt][nt] = __builtin_amdgcn_mfma_f32_16x16x32_f16(a[mt], b[nt], acc[mt][nt], 0, 0, 0);
    #pragma unroll
    for (int mt = 0; mt < 2; ++mt) {
        #pragma unroll
        for (int nt = 0; nt < 2; ++nt) {
            int col = wave * 32 + nt * 16 + l16;
            #pragma unroll
            for (int reg = 0; reg < 4; ++reg) {
                int m = mt * 16 + quad * 4 + reg;
                int f = sflat[m];
                if (f >= 0) dst[(size_t)f * D + col] = acc[mt][nt][reg];
            }
        }
    }
}

// ---------------- RoPE ----------------
__global__ __launch_bounds__(256) void rope_kernel(
    const int* __restrict__ pos, float* __restrict__ qg, float* __restrict__ kg)
{
    int gid = blockIdx.x * 256 + threadIdx.x;
    int i = gid >> 6, d2 = gid & 63;
    float p = (float)pos[i];
    float inv = powf(10000.0f, -(float)(2 * d2) / 128.0f);
    float ang = p * inv;
    float c = cosf(ang), sn = sinf(ang);
    float* q = qg + i * D;
    float q1 = q[d2], q2 = q[d2 + 64];
    q[d2]      = q1 * c - q2 * sn;
    q[d2 + 64] = q2 * c + q1 * sn;
    float* kp = kg + i * D;
    float k1 = kp[d2], k2 = kp[d2 + 64];
    kp[d2]      = k1 * c - k2 * sn;
    kp[d2 + 64] = k2 * c + k1 * sn;
}

// ---------------- streaming attention (fp32), writes fp16 A for out-proj ----------------
__global__ __launch_bounds__(64) void attn_kernel(
    const float* __restrict__ qg, const float* __restrict__ kg, const float* __restrict__ vg,
    const int* __restrict__ head_idx, const int* __restrict__ rank,
    const int* __restrict__ order, const float* __restrict__ head_w,
    _Float16* __restrict__ ao)
{
    int i = blockIdx.x;
    int lane = threadIdx.x;
    int h = head_idx[i];
    int r = rank[i];
    const int* ord = order + h * MAXL;
    float q0 = qg[i * D + lane], q1 = qg[i * D + 64 + lane];
    float m = -INFINITY, l = 0.f, o0 = 0.f, o1 = 0.f;
    for (int j = 0; j <= r; ++j) {
        int kidx = ord[j];
        float k0 = kg[kidx * D + lane], k1 = kg[kidx * D + 64 + lane];
        float part = q0 * k0 + q1 * k1;
        #pragma unroll
        for (int off = 32; off > 0; off >>= 1)
            part += __shfl_xor(part, off, 64);
        float sc = part * ATTN_SCALE;
        float mn = fmaxf(m, sc);
        float alpha = expf(m - mn);
        float w = expf(sc - mn);
        float v0 = vg[kidx * D + lane], v1 = vg[kidx * D + 64 + lane];
        l = l * alpha + w;
        o0 = o0 * alpha + w * v0;
        o1 = o1 * alpha + w * v1;
        m = mn;
    }
    float scale = head_w[i] / l;
    ao[i * D + lane]      = (_Float16)(o0 * scale);
    ao[i * D + 64 + lane] = (_Float16)(o1 * scale);
}

// ---------------- output projection via MFMA fp16: (1024 x 1024) @ Wo^T-layout ----------------
// Block: 32 rows x 64 cols, 4 waves (each wave 32x16).
__global__ __launch_bounds__(256) void out_mfma(
    const _Float16* __restrict__ A, const _Float16* __restrict__ Bt,
    float* __restrict__ C)
{
    int m0 = blockIdx.x * 32, n0 = blockIdx.y * 64;
    int tid = threadIdx.x, wave = tid >> 6, lane = tid & 63;
    int quad = lane >> 4, l16 = lane & 15;
    const _Float16* Ar[2];
    Ar[0] = A + (size_t)(m0 + l16) * 1024;
    Ar[1] = A + (size_t)(m0 + 16 + l16) * 1024;
    const _Float16* Br = Bt + (size_t)(n0 + wave * 16 + l16) * 1024;
    floatx4 acc[2] = {};
    int q8 = quad * 8;
    half8 a[2], b, a2[2], b2;
    a[0] = *(const half8*)(Ar[0] + q8);
    a[1] = *(const half8*)(Ar[1] + q8);
    b    = *(const half8*)(Br + q8);
    for (int k0 = 0; k0 < 1024 - 32; k0 += 32) {
        int kn = k0 + 32 + q8;
        a2[0] = *(const half8*)(Ar[0] + kn);
        a2[1] = *(const half8*)(Ar[1] + kn);
        b2    = *(const half8*)(Br + kn);
        acc[0] = __builtin_amdgcn_mfma_f32_16x16x32_f16(a[0], b, acc[0], 0, 0, 0);
        acc[1] = __builtin_amdgcn_mfma_f32_16x16x32_f16(a[1], b, acc[1], 0, 0, 0);
        a[0] = a2[0]; a[1] = a2[1]; b = b2;
    }
    acc[0] = __builtin_amdgcn_mfma_f32_16x16x32_f16(a[0], b, acc[0], 0, 0, 0);
    acc[1] = __builtin_amdgcn_mfma_f32_16x16x32_f16(a[1], b, acc[1], 0, 0, 0);
    int col = n0 + wave * 16 + l16;
    #pragma unroll
    for (int mt = 0; mt < 2; ++mt)
        #pragma unroll
        for (int reg = 0; reg < 4; ++reg)
            C[(size_t)(m0 + mt * 16 + quad * 4 + reg) * 1024 + col] = acc[mt][reg];
}

// ---------------- aux loss finalize ----------------
__global__ void aux_kernel(const float* __restrict__ accum, float* __restrict__ out_aux)
{
    if (threadIdx.x == 0 && blockIdx.x == 0) {
        float bal = 0.f;
        for (int h = 0; h < H; ++h)
            bal += (accum[32 + h] / (float)S) * (accum[h] / (float)S);
        bal *= (float)H;
        float ent_loss = accum[64] / (float)S;
        float z = accum[65] / (float)S * 0.01f;
        out_aux[0] = 0.01f * bal + 0.01f * ent_loss + z;
    }
}

extern "C" void kernel_launch(void* const* d_in, const int* in_sizes, int n_in,
                              void* d_out, int out_size, void* d_ws, size_t ws_size,
                              hipStream_t stream)
{
    const float* x  = (const float*)d_in[0];
    const float* Wq = (const float*)d_in[1];
    const float* Wk = (const float*)d_in[2];
    const float* Wv = (const float*)d_in[3];
    const float* Wr = (const float*)d_in[4];
    const float* Wo = (const float*)d_in[5];
    const int* head_counts = (const int*)d_in[6];
    float* out = (float*)d_out;

    // workspace layout
    float* qg     = (float*)d_ws;          // SK*D
    float* kg     = qg + SK * D;
    float* vg     = kg + SK * D;
    float* head_w = vg + SK * D;           // SK
    float* accum  = head_w + SK;           // 128
    int* head_idx = (int*)(accum + 128);   // SK
    int* rank     = head_idx + SK;         // SK
    int* pos      = rank + SK;             // SK
    int* order    = pos + SK;              // H*MAXL
    int* hlen     = order + H * MAXL;      // H (pad to 32)
    _Float16* xh   = (_Float16*)(hlen + 32);   // S*E
    _Float16* aoh  = xh + S * E;               // SK*D
    _Float16* Wqkt = aoh + SK * D;             // 3*H*D*E
    _Float16* Wot  = Wqkt + 3 * H * D * E;     // 1024*1024

    hipMemsetAsync(accum, 0, 128 * sizeof(float), stream);

    conv_x_kernel<<<S * E / 1024, 256, 0, stream>>>(x, xh);
    convT_kernel<<<dim3(16, 64), 256, 0, stream>>>(Wq, Wqkt + 0 * (size_t)HD * E, HD);
    convT_kernel<<<dim3(16, 64), 256, 0, stream>>>(Wk, Wqkt + 1 * (size_t)HD * E, HD);
    convT_kernel<<<dim3(16, 64), 256, 0, stream>>>(Wv, Wqkt + 2 * (size_t)HD * E, HD);
    convT_kernel<<<dim3(16, 16), 256, 0, stream>>>(Wo, Wot, 1024);

    router_kernel<<<S, 256, 0, stream>>>(x, Wr, head_idx, head_w, accum);
    order_kernel<<<H, 256, 0, stream>>>(head_idx, head_counts, order, rank, pos, hlen,
                                        out + (size_t)S * E);
    qkv_mfma<<<dim3(32, 3, H), 256, 0, stream>>>(xh, Wqkt, order, hlen, qg, kg, vg);
    rope_kernel<<<SK * 64 / 256, 256, 0, stream>>>(pos, qg, kg);
    attn_kernel<<<SK, 64, 0, stream>>>(qg, kg, vg, head_idx, rank, order, head_w, aoh);
    out_mfma<<<dim3(32, 16), 256, 0, stream>>>(aoh, Wot, out);
    aux_kernel<<<1, 64, 0, stream>>>(accum, out + (size_t)S * E + H);
}

// Round 3
// 415.834 us; speedup vs baseline: 1.8871x; 1.3986x over previous
//
#include <hip/hip_runtime.h>
#include <math.h>

#define S 1024
#define E 1024
#define H 32
#define KSEL 8
#define D 128
#define HD 4096      // H*D
#define SK 8192      // S*KSEL
#define MAXL 1024
#define CAP 9216     // SK + H*31 padding (per-head padded to 32)
#define ATTN_SCALE 0.08838834764831845f  // 1/sqrt(128)
#define SSTR 36
#define PSTR 40

typedef _Float16 half8 __attribute__((ext_vector_type(8)));
typedef _Float16 half4 __attribute__((ext_vector_type(4)));
typedef float floatx4 __attribute__((ext_vector_type(4)));
typedef float floatx16 __attribute__((ext_vector_type(16)));
typedef float f4 __attribute__((ext_vector_type(4)));

// ---------------- router ----------------
__global__ __launch_bounds__(256) void router_kernel(
    const float* __restrict__ x, const float* __restrict__ Wr,
    int* __restrict__ head_idx, float* __restrict__ head_w,
    float* __restrict__ accum)   // [0..31] p_sum, [32..63] f_cnt, [64] ent, [65] z
{
    int s = blockIdx.x;
    int tid = threadIdx.x;
    int h = tid & 31, i = tid >> 5;
    const float* xr = x + s * E;
    float partial = 0.f;
    for (int e = i; e < E; e += 8)
        partial += xr[e] * Wr[e * H + h];
    __shared__ float red[256];
    red[tid] = partial;
    __syncthreads();
    __shared__ float slog[H], sexp[H], scopy[H], entt[H];
    __shared__ float sm, sZ;
    if (tid < H) {
        float l = 0.f;
        #pragma unroll
        for (int j = 0; j < 8; ++j) l += red[j * 32 + tid];
        slog[tid] = l; scopy[tid] = l;
    }
    __syncthreads();
    if (tid == 0) {
        float m = slog[0];
        for (int j = 1; j < H; ++j) m = fmaxf(m, slog[j]);
        sm = m;
    }
    __syncthreads();
    if (tid < H) sexp[tid] = expf(slog[tid] - sm);
    __syncthreads();
    if (tid == 0) {
        float Z = 0.f;
        for (int j = 0; j < H; ++j) Z += sexp[j];
        sZ = Z;
        float lse = sm + logf(Z);
        atomicAdd(&accum[65], lse * lse);
    }
    __syncthreads();
    if (tid < H) {
        float p = sexp[tid] / sZ;
        atomicAdd(&accum[tid], p);
        entt[tid] = p * logf(p + 1e-8f);
    }
    __syncthreads();
    if (tid == 0) {
        float es = 0.f;
        for (int j = 0; j < H; ++j) es += entt[j];
        atomicAdd(&accum[64], es);
        float tv[KSEL]; int ti[KSEL];
        for (int j = 0; j < KSEL; ++j) {
            float bv = -INFINITY; int bi = 0;
            for (int hh = 0; hh < H; ++hh)
                if (scopy[hh] > bv) { bv = scopy[hh]; bi = hh; }
            tv[j] = bv; ti[j] = bi; scopy[bi] = -INFINITY;
        }
        float m2 = tv[0], Z2 = 0.f, w[KSEL];
        #pragma unroll
        for (int j = 0; j < KSEL; ++j) { w[j] = expf(tv[j] - m2); Z2 += w[j]; }
        #pragma unroll
        for (int j = 0; j < KSEL; ++j) {
            head_idx[s * KSEL + j] = ti[j];
            head_w[s * KSEL + j] = w[j] / Z2;
        }
        atomicAdd(&accum[32 + ti[0]], 1.0f);
    }
}

// ---------------- per-head ordered lists (ballot scan) ----------------
__global__ __launch_bounds__(256) void order_kernel(
    const int* __restrict__ head_idx, const int* __restrict__ head_counts,
    int* __restrict__ order, int* __restrict__ hlen, float* __restrict__ out_counts)
{
    int h = blockIdx.x, tid = threadIdx.x;
    int wave = tid >> 6, lane = tid & 63;
    __shared__ int wtot[4];
    int base = 0;
    int hc = head_counts[h];
    for (int c0 = 0; c0 < SK; c0 += 256) {
        int i = c0 + tid;
        bool pred = (head_idx[i] == h);
        unsigned long long mask = __ballot(pred);
        int within = __popcll(mask & ((1ull << lane) - 1ull));
        if (lane == 0) wtot[wave] = __popcll(mask);
        __syncthreads();
        int pre = 0, tot = 0;
        #pragma unroll
        for (int w = 0; w < 4; ++w) { int t = wtot[w]; if (w < wave) pre += t; tot += t; }
        if (pred) order[h * MAXL + base + pre + within] = i;
        base += tot;
        __syncthreads();
    }
    if (tid == 0) {
        hlen[h] = base;
        out_counts[h] = (float)(hc + base);
    }
}

// ---------------- per-head compact offsets (padded to 32) ----------------
__global__ void offs_kernel(const int* __restrict__ hlen, int* __restrict__ hstart)
{
    if (threadIdx.x == 0 && blockIdx.x == 0) {
        int acc = 0;
        for (int h = 0; h < H; ++h) {
            hstart[h] = acc;
            acc += (hlen[h] + 31) & ~31;
        }
    }
}

// ---------------- fp32 -> fp16 elementwise (x) ----------------
__global__ __launch_bounds__(256) void conv_x_kernel(const float* __restrict__ x,
                                                     _Float16* __restrict__ xh)
{
    int i = (blockIdx.x * 256 + threadIdx.x) * 4;
    f4 v = *(const f4*)&x[i];
    half4 o;
    o.x = (_Float16)v.x; o.y = (_Float16)v.y; o.z = (_Float16)v.z; o.w = (_Float16)v.w;
    *(half4*)&xh[i] = o;
}

// ---------------- transpose + convert: W (1024 x C fp32) -> T (C x 1024 fp16) ----------------
__global__ __launch_bounds__(256) void convT_kernel(const float* __restrict__ W,
                                                    _Float16* __restrict__ T, int C)
{
    int r0 = blockIdx.x * 64, c0 = blockIdx.y * 64;
    int t = threadIdx.x;
    __shared__ float tile[64][65];
    #pragma unroll
    for (int p = 0; p < 4; ++p) {
        int idx = p * 256 + t;
        int r = idx >> 4, cq = (idx & 15) * 4;
        f4 v = *(const f4*)&W[(size_t)(r0 + r) * C + c0 + cq];
        tile[r][cq] = v.x; tile[r][cq + 1] = v.y; tile[r][cq + 2] = v.z; tile[r][cq + 3] = v.w;
    }
    __syncthreads();
    #pragma unroll
    for (int p = 0; p < 4; ++p) {
        int idx = p * 256 + t;
        int c = idx >> 4, rq = (idx & 15) * 4;
        half4 o;
        o.x = (_Float16)tile[rq][c];
        o.y = (_Float16)tile[rq + 1][c];
        o.z = (_Float16)tile[rq + 2][c];
        o.w = (_Float16)tile[rq + 3][c];
        *(half4*)&T[(size_t)(c0 + c) * 1024 + r0 + rq] = o;
    }
}

// ---------------- gathered QKV projection via MFMA fp16, ordered outputs ----------------
// Wt layout: [qkv][h][d][e] fp16.  Block: 32 ordered slots x 128 cols, 4 waves.
// q,k -> [hb+slot][d] fp16;  v -> vT[hb*D + d*lenp + slot] fp16 (transposed).
__global__ __launch_bounds__(256) void qkv_mfma(
    const _Float16* __restrict__ xh, const _Float16* __restrict__ Wt,
    const int* __restrict__ order, const int* __restrict__ hlen,
    const int* __restrict__ hstart,
    _Float16* __restrict__ qh, _Float16* __restrict__ kh, _Float16* __restrict__ vT)
{
    int rt = blockIdx.x, qkv = blockIdx.y, h = blockIdx.z;
    int len = hlen[h], row0 = rt * 32;
    if (row0 >= len) return;
    int hb = hstart[h];
    int lenp = (len + 31) & ~31;
    int tid = threadIdx.x, wave = tid >> 6, lane = tid & 63;
    int quad = lane >> 4, l16 = lane & 15;
    __shared__ int stok[32];
    if (tid < 32) {
        int r = row0 + tid;
        stok[tid] = (r < len) ? (order[h * MAXL + r] >> 3) : 0;
    }
    __syncthreads();
    const _Float16* Arow[2];
    #pragma unroll
    for (int mt = 0; mt < 2; ++mt)
        Arow[mt] = xh + (size_t)stok[mt * 16 + l16] * E;
    const _Float16* Brow[2];
    #pragma unroll
    for (int nt = 0; nt < 2; ++nt)
        Brow[nt] = Wt + (size_t)((qkv * H + h) * D + wave * 32 + nt * 16 + l16) * E;
    floatx4 acc[2][2] = {};
    int q8 = quad * 8;
    half8 a[2], b[2], a2[2], b2[2];
    a[0] = *(const half8*)(Arow[0] + q8);
    a[1] = *(const half8*)(Arow[1] + q8);
    b[0] = *(const half8*)(Brow[0] + q8);
    b[1] = *(const half8*)(Brow[1] + q8);
    for (int k0 = 0; k0 < E - 32; k0 += 32) {
        int kn = k0 + 32 + q8;
        a2[0] = *(const half8*)(Arow[0] + kn);
        a2[1] = *(const half8*)(Arow[1] + kn);
        b2[0] = *(const half8*)(Brow[0] + kn);
        b2[1] = *(const half8*)(Brow[1] + kn);
        #pragma unroll
        for (int mt = 0; mt < 2; ++mt)
            #pragma unroll
            for (int nt = 0; nt < 2; ++nt)
                acc[mt][nt] = __builtin_amdgcn_mfma_f32_16x16x32_f16(a[mt], b[nt], acc[mt][nt], 0, 0, 0);
        a[0] = a2[0]; a[1] = a2[1]; b[0] = b2[0]; b[1] = b2[1];
    }
    #pragma unroll
    for (int mt = 0; mt < 2; ++mt)
        #pragma unroll
        for (int nt = 0; nt < 2; ++nt)
            acc[mt][nt] = __builtin_amdgcn_mfma_f32_16x16x32_f16(a[mt], b[nt], acc[mt][nt], 0, 0, 0);

    if (qkv < 2) {
        _Float16* dst = (qkv == 0) ? qh : kh;
        #pragma unroll
        for (int mt = 0; mt < 2; ++mt)
            #pragma unroll
            for (int nt = 0; nt < 2; ++nt) {
                int col = wave * 32 + nt * 16 + l16;
                #pragma unroll
                for (int reg = 0; reg < 4; ++reg) {
                    int slot = row0 + mt * 16 + quad * 4 + reg;
                    if (slot < len)
                        dst[((size_t)hb + slot) * D + col] = (_Float16)acc[mt][nt][reg];
                }
            }
    } else {
        #pragma unroll
        for (int mt = 0; mt < 2; ++mt)
            #pragma unroll
            for (int nt = 0; nt < 2; ++nt) {
                int col = wave * 32 + nt * 16 + l16;
                int slot0 = row0 + mt * 16 + quad * 4;
                _Float16* vp = vT + (size_t)hb * D + (size_t)col * lenp + slot0;
                if (slot0 + 3 < len) {
                    half4 o;
                    o.x = (_Float16)acc[mt][nt][0]; o.y = (_Float16)acc[mt][nt][1];
                    o.z = (_Float16)acc[mt][nt][2]; o.w = (_Float16)acc[mt][nt][3];
                    *(half4*)vp = o;
                } else {
                    #pragma unroll
                    for (int reg = 0; reg < 4; ++reg)
                        if (slot0 + reg < len) vp[reg] = (_Float16)acc[mt][nt][reg];
                }
            }
    }
}

// ---------------- RoPE on ordered q,k (fp16 storage, fp32 math) ----------------
__global__ __launch_bounds__(256) void rope_kernel(
    const int* __restrict__ hlen, const int* __restrict__ hstart,
    const int* __restrict__ head_counts,
    _Float16* __restrict__ qh, _Float16* __restrict__ kh)
{
    int gid = blockIdx.x * 256 + threadIdx.x;
    int sg = gid >> 6, d2 = gid & 63;
    int h = sg >> 10, r = sg & 1023;
    if (r >= hlen[h]) return;
    int p = r + head_counts[h];
    p = p < 0 ? 0 : (p > 8191 ? 8191 : p);
    float inv = powf(10000.0f, -(float)(2 * d2) / 128.0f);
    float ang = (float)p * inv;
    float c = cosf(ang), sn = sinf(ang);
    size_t off = ((size_t)hstart[h] + r) * D;
    _Float16* q = qh + off;
    float q1 = (float)q[d2], q2 = (float)q[d2 + 64];
    q[d2]      = (_Float16)(q1 * c - q2 * sn);
    q[d2 + 64] = (_Float16)(q2 * c + q1 * sn);
    _Float16* kp = kh + off;
    float k1 = (float)kp[d2], k2 = (float)kp[d2 + 64];
    kp[d2]      = (_Float16)(k1 * c - k2 * sn);
    kp[d2 + 64] = (_Float16)(k2 * c + k1 * sn);
}

// ---------------- per-head causal flash attention, MFMA 32x32x16 ----------------
// One wave per 32-row q-tile.  C/D: col=lane&31, row=(reg&3)+8*(reg>>2)+4*(lane>>5).
// A/B frags: m(or n)=lane&31, k=8*(lane>>5)+j.
__global__ __launch_bounds__(64) void attn_mfma(
    const _Float16* __restrict__ qh, const _Float16* __restrict__ kh,
    const _Float16* __restrict__ vT,
    const int* __restrict__ order, const int* __restrict__ hlen,
    const int* __restrict__ hstart, const float* __restrict__ head_w,
    _Float16* __restrict__ ao)
{
    int h = blockIdx.x >> 5, qt = blockIdx.x & 31;
    int len = hlen[h];
    int row0 = qt * 32;
    if (row0 >= len) return;
    int hb = hstart[h];
    int lenp = (len + 31) & ~31;
    int lane = threadIdx.x;
    int l32 = lane & 31, g = lane >> 5;
    int srow = lane >> 1, shalf = lane & 1;

    __shared__ float Sld[32 * SSTR];
    __shared__ _Float16 Pld[32 * PSTR];
    __shared__ float alphaLd[32];
    __shared__ float scLd[32];
    __shared__ int flatLd[32];

    if (lane < 32) {
        int r = row0 + lane;
        flatLd[lane] = (r < len) ? order[h * MAXL + r] : -1;
    }

    const _Float16* qrow = qh + ((size_t)hb + row0 + l32) * D;
    half8 qf[8];
    #pragma unroll
    for (int t = 0; t < 8; ++t) qf[t] = *(const half8*)(qrow + t * 16 + g * 8);

    floatx16 O[4] = {};
    float m_run = -INFINITY, l_run = 0.f;
    __syncthreads();

    for (int kt = 0; kt <= qt; ++kt) {
        int col0 = kt * 32;
        const _Float16* krow = kh + ((size_t)hb + col0 + l32) * D;
        half8 kf[8];
        #pragma unroll
        for (int t = 0; t < 8; ++t) kf[t] = *(const half8*)(krow + t * 16 + g * 8);
        floatx16 Sc = {};
        #pragma unroll
        for (int t = 0; t < 8; ++t)
            Sc = __builtin_amdgcn_mfma_f32_32x32x16_f16(qf[t], kf[t], Sc, 0, 0, 0);
        bool diag = (kt == qt);
        #pragma unroll
        for (int reg = 0; reg < 16; ++reg) {
            int row = (reg & 3) + 8 * (reg >> 2) + 4 * g;
            float s = Sc[reg] * ATTN_SCALE;
            if (diag && l32 > row) s = -1e30f;
            Sld[row * SSTR + l32] = s;
        }
        __syncthreads();
        const float* sp = &Sld[srow * SSTR + shalf * 16];
        float va[16];
        *(f4*)(va)      = *(const f4*)(sp);
        *(f4*)(va + 4)  = *(const f4*)(sp + 4);
        *(f4*)(va + 8)  = *(const f4*)(sp + 8);
        *(f4*)(va + 12) = *(const f4*)(sp + 12);
        float mt_ = va[0];
        #pragma unroll
        for (int j = 1; j < 16; ++j) mt_ = fmaxf(mt_, va[j]);
        mt_ = fmaxf(mt_, __shfl_xor(mt_, 1, 64));
        float m_new = fmaxf(m_run, mt_);
        float alpha = expf(m_run - m_new);
        float p[16], tsum = 0.f;
        #pragma unroll
        for (int j = 0; j < 16; ++j) { p[j] = expf(va[j] - m_new); tsum += p[j]; }
        tsum += __shfl_xor(tsum, 1, 64);
        l_run = l_run * alpha + tsum;
        m_run = m_new;
        half8 ph0, ph1;
        #pragma unroll
        for (int j = 0; j < 8; ++j) { ph0[j] = (_Float16)p[j]; ph1[j] = (_Float16)p[j + 8]; }
        *(half8*)&Pld[srow * PSTR + shalf * 16]     = ph0;
        *(half8*)&Pld[srow * PSTR + shalf * 16 + 8] = ph1;
        if (shalf == 0) alphaLd[srow] = alpha;
        __syncthreads();
        f4 al[4];
        #pragma unroll
        for (int qq = 0; qq < 4; ++qq) al[qq] = *(const f4*)&alphaLd[4 * g + 8 * qq];
        #pragma unroll
        for (int reg = 0; reg < 16; ++reg) {
            float av = al[reg >> 2][reg & 3];
            O[0][reg] *= av; O[1][reg] *= av; O[2][reg] *= av; O[3][reg] *= av;
        }
        half8 pf0 = *(const half8*)&Pld[l32 * PSTR + g * 8];
        half8 pf1 = *(const half8*)&Pld[l32 * PSTR + 16 + g * 8];
        #pragma unroll
        for (int nt = 0; nt < 4; ++nt) {
            const _Float16* vp = vT + (size_t)hb * D + (size_t)(nt * 32 + l32) * lenp + col0;
            half8 v0 = *(const half8*)(vp + g * 8);
            half8 v1 = *(const half8*)(vp + 16 + g * 8);
            O[nt] = __builtin_amdgcn_mfma_f32_32x32x16_f16(pf0, v0, O[nt], 0, 0, 0);
            O[nt] = __builtin_amdgcn_mfma_f32_32x32x16_f16(pf1, v1, O[nt], 0, 0, 0);
        }
        __syncthreads();
    }
    if (shalf == 0) {
        int flat = flatLd[srow];
        float hw = (flat >= 0) ? head_w[flat] : 0.f;
        scLd[srow] = hw / l_run;
    }
    __syncthreads();
    float scr[16]; int flr[16];
    #pragma unroll
    for (int reg = 0; reg < 16; ++reg) {
        int row = (reg & 3) + 8 * (reg >> 2) + 4 * g;
        scr[reg] = scLd[row];
        flr[reg] = flatLd[row];
    }
    #pragma unroll
    for (int nt = 0; nt < 4; ++nt) {
        int col = nt * 32 + l32;
        #pragma unroll
        for (int reg = 0; reg < 16; ++reg) {
            if (flr[reg] >= 0)
                ao[(size_t)flr[reg] * D + col] = (_Float16)(O[nt][reg] * scr[reg]);
        }
    }
}

// ---------------- output projection via MFMA fp16 ----------------
__global__ __launch_bounds__(256) void out_mfma(
    const _Float16* __restrict__ A, const _Float16* __restrict__ Bt,
    float* __restrict__ C)
{
    int m0 = blockIdx.x * 32, n0 = blockIdx.y * 64;
    int tid = threadIdx.x, wave = tid >> 6, lane = tid & 63;
    int quad = lane >> 4, l16 = lane & 15;
    const _Float16* Ar[2];
    Ar[0] = A + (size_t)(m0 + l16) * 1024;
    Ar[1] = A + (size_t)(m0 + 16 + l16) * 1024;
    const _Float16* Br = Bt + (size_t)(n0 + wave * 16 + l16) * 1024;
    floatx4 acc[2] = {};
    int q8 = quad * 8;
    half8 a[2], b, a2[2], b2;
    a[0] = *(const half8*)(Ar[0] + q8);
    a[1] = *(const half8*)(Ar[1] + q8);
    b    = *(const half8*)(Br + q8);
    for (int k0 = 0; k0 < 1024 - 32; k0 += 32) {
        int kn = k0 + 32 + q8;
        a2[0] = *(const half8*)(Ar[0] + kn);
        a2[1] = *(const half8*)(Ar[1] + kn);
        b2    = *(const half8*)(Br + kn);
        acc[0] = __builtin_amdgcn_mfma_f32_16x16x32_f16(a[0], b, acc[0], 0, 0, 0);
        acc[1] = __builtin_amdgcn_mfma_f32_16x16x32_f16(a[1], b, acc[1], 0, 0, 0);
        a[0] = a2[0]; a[1] = a2[1]; b = b2;
    }
    acc[0] = __builtin_amdgcn_mfma_f32_16x16x32_f16(a[0], b, acc[0], 0, 0, 0);
    acc[1] = __builtin_amdgcn_mfma_f32_16x16x32_f16(a[1], b, acc[1], 0, 0, 0);
    int col = n0 + wave * 16 + l16;
    #pragma unroll
    for (int mt = 0; mt < 2; ++mt)
        #pragma unroll
        for (int reg = 0; reg < 4; ++reg)
            C[(size_t)(m0 + mt * 16 + quad * 4 + reg) * 1024 + col] = acc[mt][reg];
}

// ---------------- aux loss finalize ----------------
__global__ void aux_kernel(const float* __restrict__ accum, float* __restrict__ out_aux)
{
    if (threadIdx.x == 0 && blockIdx.x == 0) {
        float bal = 0.f;
        for (int h = 0; h < H; ++h)
            bal += (accum[32 + h] / (float)S) * (accum[h] / (float)S);
        bal *= (float)H;
        float ent_loss = accum[64] / (float)S;
        float z = accum[65] / (float)S * 0.01f;
        out_aux[0] = 0.01f * bal + 0.01f * ent_loss + z;
    }
}

extern "C" void kernel_launch(void* const* d_in, const int* in_sizes, int n_in,
                              void* d_out, int out_size, void* d_ws, size_t ws_size,
                              hipStream_t stream)
{
    const float* x  = (const float*)d_in[0];
    const float* Wq = (const float*)d_in[1];
    const float* Wk = (const float*)d_in[2];
    const float* Wv = (const float*)d_in[3];
    const float* Wr = (const float*)d_in[4];
    const float* Wo = (const float*)d_in[5];
    const int* head_counts = (const int*)d_in[6];
    float* out = (float*)d_out;

    float* head_w = (float*)d_ws;                 // SK
    float* accum  = head_w + SK;                  // 128
    int* head_idx = (int*)(accum + 128);          // SK
    int* order    = head_idx + SK;                // H*MAXL
    int* hlen     = order + H * MAXL;             // 32
    int* hstart   = hlen + 32;                    // 32
    _Float16* xh   = (_Float16*)(hstart + 32);    // S*E
    _Float16* aoh  = xh + (size_t)S * E;          // SK*D
    _Float16* Wqkt = aoh + (size_t)SK * D;        // 3*HD*E
    _Float16* Wot  = Wqkt + (size_t)3 * HD * E;   // 1024*1024
    _Float16* qh   = Wot + (size_t)1024 * 1024;   // CAP*D
    _Float16* kh   = qh + (size_t)CAP * D;        // CAP*D
    _Float16* vT   = kh + (size_t)CAP * D;        // CAP*D

    hipMemsetAsync(accum, 0, 128 * sizeof(float), stream);

    conv_x_kernel<<<S * E / 1024, 256, 0, stream>>>(x, xh);
    convT_kernel<<<dim3(16, 64), 256, 0, stream>>>(Wq, Wqkt + 0 * (size_t)HD * E, HD);
    convT_kernel<<<dim3(16, 64), 256, 0, stream>>>(Wk, Wqkt + 1 * (size_t)HD * E, HD);
    convT_kernel<<<dim3(16, 64), 256, 0, stream>>>(Wv, Wqkt + 2 * (size_t)HD * E, HD);
    convT_kernel<<<dim3(16, 16), 256, 0, stream>>>(Wo, Wot, 1024);

    router_kernel<<<S, 256, 0, stream>>>(x, Wr, head_idx, head_w, accum);
    order_kernel<<<H, 256, 0, stream>>>(head_idx, head_counts, order, hlen,
                                        out + (size_t)S * E);
    offs_kernel<<<1, 64, 0, stream>>>(hlen, hstart);
    qkv_mfma<<<dim3(32, 3, H), 256, 0, stream>>>(xh, Wqkt, order, hlen, hstart, qh, kh, vT);
    rope_kernel<<<H * MAXL * 64 / 256, 256, 0, stream>>>(hlen, hstart, head_counts, qh, kh);
    attn_mfma<<<H * 32, 64, 0, stream>>>(qh, kh, vT, order, hlen, hstart, head_w, aoh);
    out_mfma<<<dim3(32, 16), 256, 0, stream>>>(aoh, Wot, out);
    aux_kernel<<<1, 64, 0, stream>>>(accum, out + (size_t)S * E + H);
}

// Round 4
// 265.199 us; speedup vs baseline: 2.9591x; 1.5680x over previous
//
#include <hip/hip_runtime.h>
#include <math.h>

#define S 1024
#define E 1024
#define H 32
#define KSEL 8
#define D 128
#define HD 4096      // H*D
#define SK 8192      // S*KSEL
#define MAXL 1024
#define CAP 9216     // SK + H*31 padding (per-head padded to 32)
#define ATTN_SCALE 0.08838834764831845f  // 1/sqrt(128)
#define SSTR 36
#define PSTR 40

typedef _Float16 half8 __attribute__((ext_vector_type(8)));
typedef _Float16 half4 __attribute__((ext_vector_type(4)));
typedef float floatx4 __attribute__((ext_vector_type(4)));
typedef float floatx16 __attribute__((ext_vector_type(16)));
typedef float f4 __attribute__((ext_vector_type(4)));

// async 16B global -> LDS (lands at wave-uniform base + lane*16)
#define GLOAD_LDS16(gsrc, ldst) \
    __builtin_amdgcn_global_load_lds( \
        (const __attribute__((address_space(1))) void*)(gsrc), \
        (__attribute__((address_space(3))) void*)(ldst), 16, 0, 0)

// ---------------- router ----------------
__global__ __launch_bounds__(256) void router_kernel(
    const float* __restrict__ x, const float* __restrict__ Wr,
    int* __restrict__ head_idx, float* __restrict__ head_w,
    float* __restrict__ accum)   // [0..31] p_sum, [32..63] f_cnt, [64] ent, [65] z
{
    int s = blockIdx.x;
    int tid = threadIdx.x;
    int h = tid & 31, i = tid >> 5;
    const float* xr = x + s * E;
    float partial = 0.f;
    for (int e = i; e < E; e += 8)
        partial += xr[e] * Wr[e * H + h];
    __shared__ float red[256];
    red[tid] = partial;
    __syncthreads();
    __shared__ float slog[H], sexp[H], scopy[H], entt[H];
    __shared__ float sm, sZ;
    if (tid < H) {
        float l = 0.f;
        #pragma unroll
        for (int j = 0; j < 8; ++j) l += red[j * 32 + tid];
        slog[tid] = l; scopy[tid] = l;
    }
    __syncthreads();
    if (tid == 0) {
        float m = slog[0];
        for (int j = 1; j < H; ++j) m = fmaxf(m, slog[j]);
        sm = m;
    }
    __syncthreads();
    if (tid < H) sexp[tid] = expf(slog[tid] - sm);
    __syncthreads();
    if (tid == 0) {
        float Z = 0.f;
        for (int j = 0; j < H; ++j) Z += sexp[j];
        sZ = Z;
        float lse = sm + logf(Z);
        atomicAdd(&accum[65], lse * lse);
    }
    __syncthreads();
    if (tid < H) {
        float p = sexp[tid] / sZ;
        atomicAdd(&accum[tid], p);
        entt[tid] = p * logf(p + 1e-8f);
    }
    __syncthreads();
    if (tid == 0) {
        float es = 0.f;
        for (int j = 0; j < H; ++j) es += entt[j];
        atomicAdd(&accum[64], es);
        float tv[KSEL]; int ti[KSEL];
        for (int j = 0; j < KSEL; ++j) {
            float bv = -INFINITY; int bi = 0;
            for (int hh = 0; hh < H; ++hh)
                if (scopy[hh] > bv) { bv = scopy[hh]; bi = hh; }
            tv[j] = bv; ti[j] = bi; scopy[bi] = -INFINITY;
        }
        float m2 = tv[0], Z2 = 0.f, w[KSEL];
        #pragma unroll
        for (int j = 0; j < KSEL; ++j) { w[j] = expf(tv[j] - m2); Z2 += w[j]; }
        #pragma unroll
        for (int j = 0; j < KSEL; ++j) {
            head_idx[s * KSEL + j] = ti[j];
            head_w[s * KSEL + j] = w[j] / Z2;
        }
        atomicAdd(&accum[32 + ti[0]], 1.0f);
    }
}

// ---------------- per-head ordered lists (ballot scan) ----------------
__global__ __launch_bounds__(256) void order_kernel(
    const int* __restrict__ head_idx, const int* __restrict__ head_counts,
    int* __restrict__ order, int* __restrict__ hlen, float* __restrict__ out_counts)
{
    int h = blockIdx.x, tid = threadIdx.x;
    int wave = tid >> 6, lane = tid & 63;
    __shared__ int wtot[4];
    int base = 0;
    int hc = head_counts[h];
    for (int c0 = 0; c0 < SK; c0 += 256) {
        int i = c0 + tid;
        bool pred = (head_idx[i] == h);
        unsigned long long mask = __ballot(pred);
        int within = __popcll(mask & ((1ull << lane) - 1ull));
        if (lane == 0) wtot[wave] = __popcll(mask);
        __syncthreads();
        int pre = 0, tot = 0;
        #pragma unroll
        for (int w = 0; w < 4; ++w) { int t = wtot[w]; if (w < wave) pre += t; tot += t; }
        if (pred) order[h * MAXL + base + pre + within] = i;
        base += tot;
        __syncthreads();
    }
    if (tid == 0) {
        hlen[h] = base;
        out_counts[h] = (float)(hc + base);
    }
}

// ---------------- per-head compact offsets (padded to 32) ----------------
__global__ void offs_kernel(const int* __restrict__ hlen, int* __restrict__ hstart)
{
    if (threadIdx.x == 0 && blockIdx.x == 0) {
        int acc = 0;
        for (int h = 0; h < H; ++h) {
            hstart[h] = acc;
            acc += (hlen[h] + 31) & ~31;
        }
    }
}

// ---------------- fp32 -> fp16 elementwise (x) ----------------
__global__ __launch_bounds__(256) void conv_x_kernel(const float* __restrict__ x,
                                                     _Float16* __restrict__ xh)
{
    int i = (blockIdx.x * 256 + threadIdx.x) * 4;
    f4 v = *(const f4*)&x[i];
    half4 o;
    o.x = (_Float16)v.x; o.y = (_Float16)v.y; o.z = (_Float16)v.z; o.w = (_Float16)v.w;
    *(half4*)&xh[i] = o;
}

// ---------------- transpose + convert: W (1024 x C fp32) -> T (C x 1024 fp16) ----------------
__global__ __launch_bounds__(256) void convT_kernel(const float* __restrict__ W,
                                                    _Float16* __restrict__ T, int C)
{
    int r0 = blockIdx.x * 64, c0 = blockIdx.y * 64;
    int t = threadIdx.x;
    __shared__ float tile[64][65];
    #pragma unroll
    for (int p = 0; p < 4; ++p) {
        int idx = p * 256 + t;
        int r = idx >> 4, cq = (idx & 15) * 4;
        f4 v = *(const f4*)&W[(size_t)(r0 + r) * C + c0 + cq];
        tile[r][cq] = v.x; tile[r][cq + 1] = v.y; tile[r][cq + 2] = v.z; tile[r][cq + 3] = v.w;
    }
    __syncthreads();
    #pragma unroll
    for (int p = 0; p < 4; ++p) {
        int idx = p * 256 + t;
        int c = idx >> 4, rq = (idx & 15) * 4;
        half4 o;
        o.x = (_Float16)tile[rq][c];
        o.y = (_Float16)tile[rq + 1][c];
        o.z = (_Float16)tile[rq + 2][c];
        o.w = (_Float16)tile[rq + 3][c];
        *(half4*)&T[(size_t)(c0 + c) * 1024 + r0 + rq] = o;
    }
}

// ---------------- gathered QKV projection: LDS double-buffered MFMA GEMM ----------------
// grid: (96 = qkv*32+h, 16 row-tiles).  Block tile 64 slots x 128 d-cols, BK=64.
// 4 waves 2x2, each wave 32x64 via mfma_f32_32x32x16_f16.
// LDS layout: per row 8 chunks of 16B, chunk c holds global chunk c^(row&7).
__global__ __launch_bounds__(256) void qkv_mfma(
    const _Float16* __restrict__ xh, const _Float16* __restrict__ Wt,
    const int* __restrict__ order, const int* __restrict__ hlen,
    const int* __restrict__ hstart,
    _Float16* __restrict__ qh, _Float16* __restrict__ kh, _Float16* __restrict__ vT)
{
    int xid = blockIdx.x;
    int qkv = xid >> 5, h = xid & 31;
    int rt = blockIdx.y;
    int len = hlen[h];
    int row0 = rt * 64;
    if (row0 >= len) return;
    int hb = hstart[h];
    int lenp = (len + 31) & ~31;
    int tid = threadIdx.x, wave = tid >> 6, lane = tid & 63;
    int wm = wave >> 1, wn = wave & 1;
    int l32 = lane & 31, g = lane >> 5;

    __shared__ _Float16 As[2][64 * 64];
    __shared__ _Float16 Bs[2][128 * 64];
    __shared__ int stok[64];

    if (tid < 64) {
        int r = row0 + tid;
        stok[tid] = (r < len) ? (order[h * MAXL + r] >> 3) : 0;
    }
    __syncthreads();

    const _Float16* Wb = Wt + (size_t)((qkv * H + h) * D) * E;

    auto stage = [&](int buf, int k0) {
        #pragma unroll
        for (int it = 0; it < 2; ++it) {
            int f = it * 256 + tid;
            int row = f >> 3, c = f & 7;
            int sc = c ^ (row & 7);
            const _Float16* src = xh + (size_t)stok[row] * E + k0 + sc * 8;
            GLOAD_LDS16(src, &As[buf][f * 8]);
        }
        #pragma unroll
        for (int it = 0; it < 4; ++it) {
            int f = it * 256 + tid;
            int row = f >> 3, c = f & 7;
            int sc = c ^ (row & 7);
            const _Float16* src = Wb + (size_t)row * E + k0 + sc * 8;
            GLOAD_LDS16(src, &Bs[buf][f * 8]);
        }
    };

    floatx16 acc[2] = {};
    int arow = wm * 32 + l32;

    auto compute = [&](int buf) {
        #pragma unroll
        for (int ks = 0; ks < 4; ++ks) {
            int wchunk = ks * 2 + g;
            half8 af = *(const half8*)&As[buf][arow * 64 + (wchunk ^ (arow & 7)) * 8];
            #pragma unroll
            for (int nf = 0; nf < 2; ++nf) {
                int brow = wn * 64 + nf * 32 + l32;
                half8 bf = *(const half8*)&Bs[buf][brow * 64 + (wchunk ^ (brow & 7)) * 8];
                acc[nf] = __builtin_amdgcn_mfma_f32_32x32x16_f16(af, bf, acc[nf], 0, 0, 0);
            }
        }
    };

    stage(0, 0);
    __syncthreads();
    int buf = 0;
    for (int k0 = 64; k0 < E; k0 += 64) {
        stage(buf ^ 1, k0);
        compute(buf);
        __syncthreads();
        buf ^= 1;
    }
    compute(buf);

    if (qkv < 2) {
        _Float16* dst = (qkv == 0) ? qh : kh;
        #pragma unroll
        for (int nf = 0; nf < 2; ++nf) {
            int col = wn * 64 + nf * 32 + l32;
            #pragma unroll
            for (int reg = 0; reg < 16; ++reg) {
                int slot = row0 + wm * 32 + (reg & 3) + 8 * (reg >> 2) + 4 * g;
                if (slot < len)
                    dst[((size_t)hb + slot) * D + col] = (_Float16)acc[nf][reg];
            }
        }
    } else {
        #pragma unroll
        for (int nf = 0; nf < 2; ++nf) {
            int col = wn * 64 + nf * 32 + l32;
            #pragma unroll
            for (int q4 = 0; q4 < 4; ++q4) {
                int slot0 = row0 + wm * 32 + 8 * q4 + 4 * g;
                _Float16* vp = vT + (size_t)hb * D + (size_t)col * lenp + slot0;
                if (slot0 + 3 < len) {
                    half4 o;
                    o.x = (_Float16)acc[nf][q4 * 4 + 0];
                    o.y = (_Float16)acc[nf][q4 * 4 + 1];
                    o.z = (_Float16)acc[nf][q4 * 4 + 2];
                    o.w = (_Float16)acc[nf][q4 * 4 + 3];
                    *(half4*)vp = o;
                } else {
                    #pragma unroll
                    for (int r2 = 0; r2 < 4; ++r2)
                        if (slot0 + r2 < len) vp[r2] = (_Float16)acc[nf][q4 * 4 + r2];
                }
            }
        }
    }
}

// ---------------- RoPE on ordered q,k (fp16 storage, fp32 math) ----------------
__global__ __launch_bounds__(256) void rope_kernel(
    const int* __restrict__ hlen, const int* __restrict__ hstart,
    const int* __restrict__ head_counts,
    _Float16* __restrict__ qh, _Float16* __restrict__ kh)
{
    int gid = blockIdx.x * 256 + threadIdx.x;
    int sg = gid >> 6, d2 = gid & 63;
    int h = sg >> 10, r = sg & 1023;
    if (r >= hlen[h]) return;
    int p = r + head_counts[h];
    p = p < 0 ? 0 : (p > 8191 ? 8191 : p);
    float inv = powf(10000.0f, -(float)(2 * d2) / 128.0f);
    float ang = (float)p * inv;
    float c = cosf(ang), sn = sinf(ang);
    size_t off = ((size_t)hstart[h] + r) * D;
    _Float16* q = qh + off;
    float q1 = (float)q[d2], q2 = (float)q[d2 + 64];
    q[d2]      = (_Float16)(q1 * c - q2 * sn);
    q[d2 + 64] = (_Float16)(q2 * c + q1 * sn);
    _Float16* kp = kh + off;
    float k1 = (float)kp[d2], k2 = (float)kp[d2 + 64];
    kp[d2]      = (_Float16)(k1 * c - k2 * sn);
    kp[d2 + 64] = (_Float16)(k2 * c + k1 * sn);
}

// ---------------- per-head causal flash attention, MFMA 32x32x16 ----------------
__global__ __launch_bounds__(64) void attn_mfma(
    const _Float16* __restrict__ qh, const _Float16* __restrict__ kh,
    const _Float16* __restrict__ vT,
    const int* __restrict__ order, const int* __restrict__ hlen,
    const int* __restrict__ hstart, const float* __restrict__ head_w,
    _Float16* __restrict__ ao)
{
    int h = blockIdx.x >> 5, qt = blockIdx.x & 31;
    int len = hlen[h];
    int row0 = qt * 32;
    if (row0 >= len) return;
    int hb = hstart[h];
    int lenp = (len + 31) & ~31;
    int lane = threadIdx.x;
    int l32 = lane & 31, g = lane >> 5;
    int srow = lane >> 1, shalf = lane & 1;

    __shared__ float Sld[32 * SSTR];
    __shared__ _Float16 Pld[32 * PSTR];
    __shared__ float alphaLd[32];
    __shared__ float scLd[32];
    __shared__ int flatLd[32];

    if (lane < 32) {
        int r = row0 + lane;
        flatLd[lane] = (r < len) ? order[h * MAXL + r] : -1;
    }

    const _Float16* qrow = qh + ((size_t)hb + row0 + l32) * D;
    half8 qf[8];
    #pragma unroll
    for (int t = 0; t < 8; ++t) qf[t] = *(const half8*)(qrow + t * 16 + g * 8);

    floatx16 O[4] = {};
    float m_run = -INFINITY, l_run = 0.f;
    __syncthreads();

    for (int kt = 0; kt <= qt; ++kt) {
        int col0 = kt * 32;
        const _Float16* krow = kh + ((size_t)hb + col0 + l32) * D;
        half8 kf[8];
        #pragma unroll
        for (int t = 0; t < 8; ++t) kf[t] = *(const half8*)(krow + t * 16 + g * 8);
        floatx16 Sc = {};
        #pragma unroll
        for (int t = 0; t < 8; ++t)
            Sc = __builtin_amdgcn_mfma_f32_32x32x16_f16(qf[t], kf[t], Sc, 0, 0, 0);
        bool diag = (kt == qt);
        #pragma unroll
        for (int reg = 0; reg < 16; ++reg) {
            int row = (reg & 3) + 8 * (reg >> 2) + 4 * g;
            float s = Sc[reg] * ATTN_SCALE;
            if (diag && l32 > row) s = -1e30f;
            Sld[row * SSTR + l32] = s;
        }
        __syncthreads();
        const float* sp = &Sld[srow * SSTR + shalf * 16];
        float va[16];
        *(f4*)(va)      = *(const f4*)(sp);
        *(f4*)(va + 4)  = *(const f4*)(sp + 4);
        *(f4*)(va + 8)  = *(const f4*)(sp + 8);
        *(f4*)(va + 12) = *(const f4*)(sp + 12);
        float mt_ = va[0];
        #pragma unroll
        for (int j = 1; j < 16; ++j) mt_ = fmaxf(mt_, va[j]);
        mt_ = fmaxf(mt_, __shfl_xor(mt_, 1, 64));
        float m_new = fmaxf(m_run, mt_);
        float alpha = expf(m_run - m_new);
        float p[16], tsum = 0.f;
        #pragma unroll
        for (int j = 0; j < 16; ++j) { p[j] = expf(va[j] - m_new); tsum += p[j]; }
        tsum += __shfl_xor(tsum, 1, 64);
        l_run = l_run * alpha + tsum;
        m_run = m_new;
        half8 ph0, ph1;
        #pragma unroll
        for (int j = 0; j < 8; ++j) { ph0[j] = (_Float16)p[j]; ph1[j] = (_Float16)p[j + 8]; }
        *(half8*)&Pld[srow * PSTR + shalf * 16]     = ph0;
        *(half8*)&Pld[srow * PSTR + shalf * 16 + 8] = ph1;
        if (shalf == 0) alphaLd[srow] = alpha;
        __syncthreads();
        f4 al[4];
        #pragma unroll
        for (int qq = 0; qq < 4; ++qq) al[qq] = *(const f4*)&alphaLd[4 * g + 8 * qq];
        #pragma unroll
        for (int reg = 0; reg < 16; ++reg) {
            float av = al[reg >> 2][reg & 3];
            O[0][reg] *= av; O[1][reg] *= av; O[2][reg] *= av; O[3][reg] *= av;
        }
        half8 pf0 = *(const half8*)&Pld[l32 * PSTR + g * 8];
        half8 pf1 = *(const half8*)&Pld[l32 * PSTR + 16 + g * 8];
        #pragma unroll
        for (int nt = 0; nt < 4; ++nt) {
            const _Float16* vp = vT + (size_t)hb * D + (size_t)(nt * 32 + l32) * lenp + col0;
            half8 v0 = *(const half8*)(vp + g * 8);
            half8 v1 = *(const half8*)(vp + 16 + g * 8);
            O[nt] = __builtin_amdgcn_mfma_f32_32x32x16_f16(pf0, v0, O[nt], 0, 0, 0);
            O[nt] = __builtin_amdgcn_mfma_f32_32x32x16_f16(pf1, v1, O[nt], 0, 0, 0);
        }
        __syncthreads();
    }
    if (shalf == 0) {
        int flat = flatLd[srow];
        float hw = (flat >= 0) ? head_w[flat] : 0.f;
        scLd[srow] = hw / l_run;
    }
    __syncthreads();
    float scr[16]; int flr[16];
    #pragma unroll
    for (int reg = 0; reg < 16; ++reg) {
        int row = (reg & 3) + 8 * (reg >> 2) + 4 * g;
        scr[reg] = scLd[row];
        flr[reg] = flatLd[row];
    }
    #pragma unroll
    for (int nt = 0; nt < 4; ++nt) {
        int col = nt * 32 + l32;
        #pragma unroll
        for (int reg = 0; reg < 16; ++reg) {
            if (flr[reg] >= 0)
                ao[(size_t)flr[reg] * D + col] = (_Float16)(O[nt][reg] * scr[reg]);
        }
    }
}

// ---------------- output projection: dense LDS double-buffered MFMA GEMM ----------------
// C[1024x1024] = A[1024x1024] @ Bt[1024n x 1024k].  grid (16 n-tiles, 16 m-tiles).
// Block tile 64x64, BK=64, 4 waves 2x2, each 32x32.
__global__ __launch_bounds__(256) void out_mfma(
    const _Float16* __restrict__ A, const _Float16* __restrict__ Bt,
    float* __restrict__ C)
{
    int n0 = blockIdx.x * 64, m0 = blockIdx.y * 64;
    int tid = threadIdx.x, wave = tid >> 6, lane = tid & 63;
    int wm = wave >> 1, wn = wave & 1;
    int l32 = lane & 31, g = lane >> 5;

    __shared__ _Float16 As[2][64 * 64];
    __shared__ _Float16 Bs[2][64 * 64];

    auto stage = [&](int buf, int k0) {
        #pragma unroll
        for (int it = 0; it < 2; ++it) {
            int f = it * 256 + tid;
            int row = f >> 3, c = f & 7;
            int sc = c ^ (row & 7);
            GLOAD_LDS16(A + (size_t)(m0 + row) * 1024 + k0 + sc * 8, &As[buf][f * 8]);
        }
        #pragma unroll
        for (int it = 0; it < 2; ++it) {
            int f = it * 256 + tid;
            int row = f >> 3, c = f & 7;
            int sc = c ^ (row & 7);
            GLOAD_LDS16(Bt + (size_t)(n0 + row) * 1024 + k0 + sc * 8, &Bs[buf][f * 8]);
        }
    };

    floatx16 acc = {};
    int arow = wm * 32 + l32;
    int brow = wn * 32 + l32;

    auto compute = [&](int buf) {
        #pragma unroll
        for (int ks = 0; ks < 4; ++ks) {
            int wchunk = ks * 2 + g;
            half8 af = *(const half8*)&As[buf][arow * 64 + (wchunk ^ (arow & 7)) * 8];
            half8 bf = *(const half8*)&Bs[buf][brow * 64 + (wchunk ^ (brow & 7)) * 8];
            acc = __builtin_amdgcn_mfma_f32_32x32x16_f16(af, bf, acc, 0, 0, 0);
        }
    };

    stage(0, 0);
    __syncthreads();
    int buf = 0;
    for (int k0 = 64; k0 < 1024; k0 += 64) {
        stage(buf ^ 1, k0);
        compute(buf);
        __syncthreads();
        buf ^= 1;
    }
    compute(buf);

    int col = n0 + wn * 32 + l32;
    #pragma unroll
    for (int reg = 0; reg < 16; ++reg) {
        int row = m0 + wm * 32 + (reg & 3) + 8 * (reg >> 2) + 4 * g;
        C[(size_t)row * 1024 + col] = acc[reg];
    }
}

// ---------------- aux loss finalize ----------------
__global__ void aux_kernel(const float* __restrict__ accum, float* __restrict__ out_aux)
{
    if (threadIdx.x == 0 && blockIdx.x == 0) {
        float bal = 0.f;
        for (int h = 0; h < H; ++h)
            bal += (accum[32 + h] / (float)S) * (accum[h] / (float)S);
        bal *= (float)H;
        float ent_loss = accum[64] / (float)S;
        float z = accum[65] / (float)S * 0.01f;
        out_aux[0] = 0.01f * bal + 0.01f * ent_loss + z;
    }
}

extern "C" void kernel_launch(void* const* d_in, const int* in_sizes, int n_in,
                              void* d_out, int out_size, void* d_ws, size_t ws_size,
                              hipStream_t stream)
{
    const float* x  = (const float*)d_in[0];
    const float* Wq = (const float*)d_in[1];
    const float* Wk = (const float*)d_in[2];
    const float* Wv = (const float*)d_in[3];
    const float* Wr = (const float*)d_in[4];
    const float* Wo = (const float*)d_in[5];
    const int* head_counts = (const int*)d_in[6];
    float* out = (float*)d_out;

    float* head_w = (float*)d_ws;                 // SK
    float* accum  = head_w + SK;                  // 128
    int* head_idx = (int*)(accum + 128);          // SK
    int* order    = head_idx + SK;                // H*MAXL
    int* hlen     = order + H * MAXL;             // 32
    int* hstart   = hlen + 32;                    // 32
    _Float16* xh   = (_Float16*)(hstart + 32);    // S*E
    _Float16* aoh  = xh + (size_t)S * E;          // SK*D
    _Float16* Wqkt = aoh + (size_t)SK * D;        // 3*HD*E
    _Float16* Wot  = Wqkt + (size_t)3 * HD * E;   // 1024*1024
    _Float16* qh   = Wot + (size_t)1024 * 1024;   // CAP*D
    _Float16* kh   = qh + (size_t)CAP * D;        // CAP*D
    _Float16* vT   = kh + (size_t)CAP * D;        // CAP*D

    hipMemsetAsync(accum, 0, 128 * sizeof(float), stream);

    conv_x_kernel<<<S * E / 1024, 256, 0, stream>>>(x, xh);
    convT_kernel<<<dim3(16, 64), 256, 0, stream>>>(Wq, Wqkt + 0 * (size_t)HD * E, HD);
    convT_kernel<<<dim3(16, 64), 256, 0, stream>>>(Wk, Wqkt + 1 * (size_t)HD * E, HD);
    convT_kernel<<<dim3(16, 64), 256, 0, stream>>>(Wv, Wqkt + 2 * (size_t)HD * E, HD);
    convT_kernel<<<dim3(16, 16), 256, 0, stream>>>(Wo, Wot, 1024);

    router_kernel<<<S, 256, 0, stream>>>(x, Wr, head_idx, head_w, accum);
    order_kernel<<<H, 256, 0, stream>>>(head_idx, head_counts, order, hlen,
                                        out + (size_t)S * E);
    offs_kernel<<<1, 64, 0, stream>>>(hlen, hstart);
    qkv_mfma<<<dim3(96, 16), 256, 0, stream>>>(xh, Wqkt, order, hlen, hstart, qh, kh, vT);
    rope_kernel<<<H * MAXL * 64 / 256, 256, 0, stream>>>(hlen, hstart, head_counts, qh, kh);
    attn_mfma<<<H * 32, 64, 0, stream>>>(qh, kh, vT, order, hlen, hstart, head_w, aoh);
    out_mfma<<<dim3(16, 16), 256, 0, stream>>>(aoh, Wot, out);
    aux_kernel<<<1, 64, 0, stream>>>(accum, out + (size_t)S * E + H);
}